// Round 6
// baseline (851.392 us; speedup 1.0000x reference)
//
#include <hip/hip_runtime.h>
#include <stdint.h>
#include <stddef.h>

// CNNLSTM: embed -> conv1d(K=5) -> ReLU -> maxpool4 -> LSTM(T=1023,H=128) -> fc(2)
// Inputs: x int32; all float tensors float32. Output f32.
// Internals: bf16 MFMA for conv + input-projection GEMMs; f16 MFMA recurrence.

typedef __bf16 bf16;
typedef __bf16 bf16x8 __attribute__((ext_vector_type(8)));
typedef float  f32x4  __attribute__((ext_vector_type(4)));
typedef _Float16 f16;
typedef f16 f16x2 __attribute__((ext_vector_type(2)));
typedef f16 f16x4 __attribute__((ext_vector_type(4)));
typedef f16 f16x8 __attribute__((ext_vector_type(8)));

#define MFMA16(a, b, c)  __builtin_amdgcn_mfma_f32_16x16x32_bf16((a), (b), (c), 0, 0, 0)
#define MFMA16H(a, b, c) __builtin_amdgcn_mfma_f32_16x16x32_f16((a), (b), (c), 0, 0, 0)

// Barrier draining LDS (lgkm) but NOT in-flight global prefetch loads.
#define LGKM_BARRIER() asm volatile("s_waitcnt lgkmcnt(0)\ns_barrier" ::: "memory")

// ---------------- ws layout (bytes) ----------------
#define WS_BT     0               // conv weights repacked [64][640] bf16 =    81,920
#define WS_WIHB   81920           // w_ih bf16 [512][64]                  =    65,536
#define WS_POOLED 278528          // pooled bf16 [64][1024][64]           = 8,388,608
#define WS_EMB    8667136         // emb bf16 [20000][128]                = 5,120,000
#define WS_XG     8667136         // xgc f16 [64][128][128][4][8]         = 67,108,864
// (xgc overlaps emb_bf16: emb dead after conv_pool)

// ============ prep A: emb f32 -> bf16 ============
__global__ void emb_cvt_k(const float* __restrict__ emb, bf16* __restrict__ embb) {
    int g = blockIdx.x * 256 + threadIdx.x;
    f32x4 v = *(const f32x4*)(emb + g * 4);
    bf16* d = embb + g * 4;
    d[0] = (bf16)v[0]; d[1] = (bf16)v[1]; d[2] = (bf16)v[2]; d[3] = (bf16)v[3];
}

// ============ prep B: conv_w repack->bf16; w_ih->bf16 ============
__global__ void prep_small_k(const float* __restrict__ conv_w, bf16* __restrict__ bt,
                             const float* __restrict__ w_ih, bf16* __restrict__ w_ihb) {
    int g = blockIdx.x * 256 + threadIdx.x;
    if (g < 64 * 640) {
        int f = g / 640, kk = g - f * 640;
        int k = kk >> 7, e = kk & 127;
        bt[g] = (bf16)conv_w[(f * 128 + e) * 5 + k];
    } else {
        int h = g - 64 * 640;
        if (h < 512 * 64) w_ihb[h] = (bf16)w_ih[h];
    }
}

// ============ kernel 1: embed-gather + conv + ReLU + pool4 ============
__global__ __launch_bounds__(256, 2) void conv_pool_k(
    const int* __restrict__ x, const bf16* __restrict__ embb,
    const bf16* __restrict__ bt, const float* __restrict__ conv_b,
    bf16* __restrict__ pooled)
{
    __shared__ bf16 T[144 * 136];  // 136 = 128 + 8 pad
    const int b   = blockIdx.x >> 5;
    const int l0  = (blockIdx.x & 31) << 7;
    const int tid = threadIdx.x;
    const int ln  = tid & 63, w = tid >> 6;
    const int l15 = ln & 15, quad = ln >> 4;
    const int f   = w * 16 + l15;

    bf16x8 bfrag[20];
    #pragma unroll
    for (int kc = 0; kc < 20; ++kc) {
        uint4 v = *(const uint4*)(bt + f * 640 + kc * 32 + quad * 8);
        bfrag[kc] = __builtin_bit_cast(bf16x8, v);
    }
    const float cb = conv_b[f];

    #pragma unroll
    for (int p = 0; p < 9; ++p) {
        int r = p * 16 + (tid >> 4);
        int cg = tid & 15;
        int token = l0 + r; if (token > 4095) token = 4095;
        int idx = x[b * 4096 + token];
        uint4 v = *(const uint4*)(embb + idx * 128 + cg * 8);
        *(uint4*)(&T[r * 136 + cg * 8]) = v;
    }
    __syncthreads();

    f32x4 acc[8];
    #pragma unroll
    for (int tm = 0; tm < 8; ++tm) acc[tm] = (f32x4){0.f, 0.f, 0.f, 0.f};

    #pragma unroll
    for (int kc = 0; kc < 20; ++kc) {
        const int ktap = kc >> 2;
        const int ecol = (kc & 3) * 32 + quad * 8;
        #pragma unroll
        for (int tm = 0; tm < 8; ++tm) {
            int row = tm * 16 + l15 + ktap;
            bf16x8 a = *(const bf16x8*)(&T[row * 136 + ecol]);
            acc[tm] = MFMA16(a, bfrag[kc], acc[tm]);
        }
    }

    #pragma unroll
    for (int tm = 0; tm < 8; ++tm) {
        float mx = fmaxf(fmaxf(acc[tm][0], acc[tm][1]), fmaxf(acc[tm][2], acc[tm][3]));
        mx = fmaxf(mx + cb, 0.f);
        int t = (l0 >> 2) + tm * 4 + quad;
        if (t < 1023) pooled[(b * 1024 + t) * 64 + f] = (bf16)mx;
    }
}

// ============ kernel 2: xgc = pooled @ w_ih^T + (b_ih+b_hh), chunk-layout f16 ============
// xgc[b][c][unit][gate][j], t = c*8+j. LSTM lane reads 64 contiguous B/chunk.
__global__ __launch_bounds__(256, 2) void xg_gemm_k(
    const bf16* __restrict__ pooled, const bf16* __restrict__ w_ihb,
    const float* __restrict__ b_ih, const float* __restrict__ b_hh,
    f16* __restrict__ xg)
{
    __shared__ bf16 A[256 * 72];  // 72 = 64 + 8 pad
    const int m0  = blockIdx.x * 256;
    const int tid = threadIdx.x;
    const int ln  = tid & 63, w = tid >> 6;
    const int l15 = ln & 15, quad = ln >> 4;

    #pragma unroll
    for (int i = 0; i < 8; ++i) {
        int task = i * 256 + tid;
        int row = task >> 3, ch = task & 7;
        uint4 v = *(const uint4*)(pooled + (m0 + row) * 64 + ch * 8);
        *(uint4*)(&A[row * 72 + ch * 8]) = v;
    }
    __syncthreads();

    bf16x8 afrag[4][2];
    #pragma unroll
    for (int mt = 0; mt < 4; ++mt)
        #pragma unroll
        for (int kc = 0; kc < 2; ++kc)
            afrag[mt][kc] = *(const bf16x8*)(&A[((w * 4 + mt) * 16 + l15) * 72 + kc * 32 + quad * 8]);

    const int b_idx = m0 >> 10;
    const int tbase = m0 & 1023;

    for (int nt = 0; nt < 32; ++nt) {
        const int nn = nt * 16 + l15;
        uint4 v0 = *(const uint4*)(w_ihb + nn * 64 + quad * 8);
        uint4 v1 = *(const uint4*)(w_ihb + nn * 64 + 32 + quad * 8);
        bf16x8 bf0 = __builtin_bit_cast(bf16x8, v0);
        bf16x8 bf1 = __builtin_bit_cast(bf16x8, v1);
        const float bias = b_ih[nn] + b_hh[nn];
        const int unit = nn & 127, gate = nn >> 7;
        #pragma unroll
        for (int mt = 0; mt < 4; ++mt) {
            f32x4 acc = (f32x4){0.f, 0.f, 0.f, 0.f};
            acc = MFMA16(afrag[mt][0], bf0, acc);
            acc = MFMA16(afrag[mt][1], bf1, acc);
            int t0 = tbase + (w * 4 + mt) * 16 + quad * 4;   // t0 % 4 == 0
            f16x4 sv = {(f16)(acc[0] + bias), (f16)(acc[1] + bias),
                        (f16)(acc[2] + bias), (f16)(acc[3] + bias)};
            size_t off = (((size_t)(b_idx * 128 + (t0 >> 3)) * 128 + unit) * 4 + gate) * 8 + (t0 & 7);
            *(f16x4*)(xg + off) = sv;   // 8B store, (t0&7) in {0,4}
        }
    }
}

// ============ kernel 3: LSTM recurrence (f16 MFMA) + fc head ============
// 8 WGs x 1024 threads (16 waves = 4 waves/EU). WG handles 8 batches.
// Evidence R1/R2/R5: step = issue/SIMD + unhidden serial chain; the chain
// (~600cyc: write-drain+barrier+ds_read+mfma+act) shrinks with waves/SIMD
// (2 waves hid ~340cyc vs 1). This pushes to 4 waves/SIMD and cuts per-lane
// work: wave w owns units w*8..w*8+7 = 2 tiles x 4 kc = 8 MFMA/wave/step.
// TILE ROWS = unit x gate (row = u_local*4 + g): lane (quad,l15) holds ALL
// 4 GATES of one unit at compile-time reg indices -> extraction is 4 cndmask
// (vs 28 in R5). Cols = 8 batches x 2 reps; rep selects the tile (unit sub-
// group) -> bijective lane<->cell, 1 act chain/lane, zero redundancy
// (1024 lanes = 8 batches x 128 units). Weights 32 VGPR/lane; total live
// ~110 <= 128 (4-wave/EU budget) -> no spill (R5's VGPR=128 symptom).
// h LDS [2][8][136] f16 (272B batch stride -> <=4-way bank alias on b128).
__device__ inline float sigm_(float v) {
    return __builtin_amdgcn_rcpf(1.f + __builtin_amdgcn_exp2f(-1.4426950408889634f * v));
}
__device__ inline float tanh_(float v) {
    return 1.f - 2.f * __builtin_amdgcn_rcpf(1.f + __builtin_amdgcn_exp2f(2.8853901817779268f * v));
}

__global__ __launch_bounds__(1024, 4) __attribute__((amdgpu_waves_per_eu(4, 4)))
void lstm_fc_k(
    const f16* __restrict__ xgc, const float* __restrict__ w_hh,
    const float* __restrict__ fc_w, const float* __restrict__ fc_b,
    float* __restrict__ out)
{
    __shared__ __align__(16) f16 hbuf[2][8][136];   // [p][batch][136]; 272B stride
    const int b0   = blockIdx.x << 3;
    const int t    = threadIdx.x;     // 0..1023
    const int w    = t >> 6;          // wave 0..15 -> units w*8..w*8+7
    const int ln   = t & 63;
    const int l15  = ln & 15, quad = ln >> 4;
    const int bb   = l15 >> 1;        // batch sub 0..7 (D col group)
    const int rep  = l15 & 1;         // tile select (unit sub-group)
    const int u    = w * 8 + rep * 4 + quad;  // unit of this lane (bijective with bb)

    // ---- A fragments: wa[tile][kc]; row l15 of tile tt = (u_local = l15>>2,
    // gate = l15&3) -> W_hh[(l15&3)*128 + w*8 + tt*4 + (l15>>2)][kc*32+quad*8+j]
    f16x8 wa[2][4];
    #pragma unroll
    for (int tt = 0; tt < 2; ++tt)
        #pragma unroll
        for (int kc = 0; kc < 4; ++kc) {
            const float* wr = w_hh + (size_t)((l15 & 3) * 128 + w * 8 + tt * 4 + (l15 >> 2)) * 128
                            + kc * 32 + quad * 8;
            f32x4 v0 = *(const f32x4*)(wr);
            f32x4 v1 = *(const f32x4*)(wr + 4);
            wa[tt][kc] = (f16x8){(f16)v0[0], (f16)v0[1], (f16)v0[2], (f16)v0[3],
                                 (f16)v1[0], (f16)v1[1], (f16)v1[2], (f16)v1[3]};
        }
    #pragma unroll
    for (int tt = 0; tt < 2; ++tt)
        #pragma unroll
        for (int kc = 0; kc < 4; ++kc) {
            uint4 r = __builtin_bit_cast(uint4, wa[tt][kc]);
            asm volatile("" : "+v"(r.x), "+v"(r.y), "+v"(r.z), "+v"(r.w));  // pin
            wa[tt][kc] = __builtin_bit_cast(f16x8, r);
        }

    // xq for this lane's (batch, unit): xgc[b0+bb][ch][u][g][j]
    const f16* xb = xgc + (size_t)(b0 + bb) * 524288 + (size_t)u * 32;
    f16x8 xq0 = *(const f16x8*)(xb);
    f16x8 xq1 = *(const f16x8*)(xb + 8);
    f16x8 xq2 = *(const f16x8*)(xb + 16);
    f16x8 xq3 = *(const f16x8*)(xb + 24);
    f16x8 nx0, nx1, nx2, nx3;

    // B-frag read bases (p=0/1) and h write addrs (step p writes hbuf[p^1])
    const char* rb0 = (const char*)hbuf + bb * 272 + quad * 16;
    const char* rb1 = rb0 + 2176;
    f16* wb0 = (f16*)((char*)hbuf + 2176 + bb * 272 + u * 2);  // p=0 -> hbuf[1]
    f16* wb1 = (f16*)((char*)hbuf +        bb * 272 + u * 2);  // p=1 -> hbuf[0]

    if (t < 544) ((uint32_t*)hbuf)[t] = 0u;   // zero hbuf[0] (2176B)
    float cst = 0.f;
    LGKM_BARRIER();

    const f32x4 zf = (f32x4){0.f, 0.f, 0.f, 0.f};

    auto step = [&](int j, int p) {
        const char* rb = p ? rb1 : rb0;
        f16x8 hb0 = *(const f16x8*)(rb);
        f16x8 hb1 = *(const f16x8*)(rb + 64);
        f16x8 hb2 = *(const f16x8*)(rb + 128);
        f16x8 hb3 = *(const f16x8*)(rb + 192);
        // 2 independent 4-deep MFMA chains
        f32x4 a0 = MFMA16H(wa[0][0], hb0, zf);
        f32x4 a1 = MFMA16H(wa[1][0], hb0, zf);
        a0 = MFMA16H(wa[0][1], hb1, a0);
        a1 = MFMA16H(wa[1][1], hb1, a1);
        a0 = MFMA16H(wa[0][2], hb2, a0);
        a1 = MFMA16H(wa[1][2], hb2, a1);
        a0 = MFMA16H(wa[0][3], hb3, a0);
        a1 = MFMA16H(wa[1][3], hb3, a1);
        // lane's cell: tile = rep (1 cndmask per gate-reg; indices compile-time)
        float p0 = rep ? a1[0] : a0[0];
        float p1 = rep ? a1[1] : a0[1];
        float p2 = rep ? a1[2] : a0[2];
        float p3 = rep ? a1[3] : a0[3];
        float ig = sigm_(p0 + (float)xq0[j]);
        float fg = sigm_(p1 + (float)xq1[j]);
        float gg = tanh_(p2 + (float)xq2[j]);
        float og = sigm_(p3 + (float)xq3[j]);
        cst = fg * cst + ig * gg;
        float hn = og * tanh_(cst);
        *(p ? wb1 : wb0) = (f16)hn;
        LGKM_BARRIER();
    };

    #pragma unroll 1
    for (int ch = 0; ch < 127; ++ch) {
        // prefetch next chunk (vmcnt: not drained by the lgkm barrier)
        const f16* nb = xb + (size_t)(ch + 1) * 4096;
        nx0 = *(const f16x8*)(nb);
        nx1 = *(const f16x8*)(nb + 8);
        nx2 = *(const f16x8*)(nb + 16);
        nx3 = *(const f16x8*)(nb + 24);
        #pragma unroll
        for (int j = 0; j < 8; ++j) step(j, j & 1);
        xq0 = nx0; xq1 = nx1; xq2 = nx2; xq3 = nx3;
    }
    #pragma unroll
    for (int j = 0; j < 7; ++j) step(j, j & 1);   // steps 1016..1022; final h -> hbuf[1]

    // fc: out[b0+bbf][c2] = h_T . fc_w[c2] + fc_b[c2]   (h_T in hbuf[1])
    // wave w handles combo (bbf = w>>1, c2 = w&1); lane sums 2 units.
    {
        int bbf = w >> 1, c2 = w & 1;
        const f16* hrow = (const f16*)((const char*)hbuf + 2176 + bbf * 272);
        float pr = (float)hrow[ln] * fc_w[c2 * 128 + ln]
                 + (float)hrow[64 + ln] * fc_w[c2 * 128 + 64 + ln];
        #pragma unroll
        for (int off = 32; off > 0; off >>= 1) pr += __shfl_down(pr, off, 64);
        if (ln == 0) out[(b0 + bbf) * 2 + c2] = pr + fc_b[c2];
    }
}

// ============================ launcher ============================
extern "C" void kernel_launch(void* const* d_in, const int* in_sizes, int n_in,
                              void* d_out, int out_size, void* d_ws, size_t ws_size,
                              hipStream_t stream) {
    const int*   x      = (const int*)d_in[0];
    const float* emb    = (const float*)d_in[1];
    const float* conv_w = (const float*)d_in[2];
    const float* conv_b = (const float*)d_in[3];
    const float* w_ih   = (const float*)d_in[4];
    const float* w_hh   = (const float*)d_in[5];
    const float* b_ih   = (const float*)d_in[6];
    const float* b_hh   = (const float*)d_in[7];
    const float* fc_w   = (const float*)d_in[8];
    const float* fc_b   = (const float*)d_in[9];
    float* out = (float*)d_out;

    char* ws = (char*)d_ws;
    bf16* bt     = (bf16*)(ws + WS_BT);
    bf16* w_ihb  = (bf16*)(ws + WS_WIHB);
    bf16* pooled = (bf16*)(ws + WS_POOLED);
    bf16* embb   = (bf16*)(ws + WS_EMB);
    f16*  xg     = (f16*)(ws + WS_XG);   // overlaps embb (emb dead after conv_pool)

    emb_cvt_k<<<2500, 256, 0, stream>>>(emb, embb);
    prep_small_k<<<288, 256, 0, stream>>>(conv_w, bt, w_ih, w_ihb);
    conv_pool_k<<<2048, 256, 0, stream>>>(x, embb, bt, conv_b, pooled);
    xg_gemm_k<<<256, 256, 0, stream>>>(pooled, w_ihb, b_ih, b_hh, xg);
    lstm_fc_k<<<8, 1024, 0, stream>>>(xg, w_hh, fc_w, fc_b, out);
}

// Round 8
// 592.542 us; speedup vs baseline: 1.4368x; 1.4368x over previous
//
#include <hip/hip_runtime.h>
#include <stdint.h>
#include <stddef.h>

// CNNLSTM: embed -> conv1d(K=5) -> ReLU -> maxpool4 -> LSTM(T=1023,H=128) -> fc(2)
// Inputs: x int32; all float tensors float32. Output f32.
// Internals: bf16 MFMA for conv + fused input-projection GEMM; f16 MFMA recurrence.
// R8: 3 dispatches. R7's fused kernel raced: it wrote xg while reading embb,
// and WS_XG == WS_EMB (overlap was only safe when separate dispatches ordered
// them). Fix: gather emb f32 DIRECTLY in the fused kernel (convert to bf16
// in-register -- identical rounding to the old emb_cvt path) -> embb deleted,
// nothing aliases xg, and emb_cvt's 2500-block dispatch disappears.
// lstm_fc_k is byte-identical to the R2 kernel that measured 463.7us.

typedef __bf16 bf16;
typedef __bf16 bf16x8 __attribute__((ext_vector_type(8)));
typedef float  f32x4  __attribute__((ext_vector_type(4)));
typedef _Float16 f16;
typedef f16 f16x2 __attribute__((ext_vector_type(2)));
typedef f16 f16x4 __attribute__((ext_vector_type(4)));
typedef f16 f16x8 __attribute__((ext_vector_type(8)));

#define MFMA16(a, b, c)  __builtin_amdgcn_mfma_f32_16x16x32_bf16((a), (b), (c), 0, 0, 0)
#define MFMA16H(a, b, c) __builtin_amdgcn_mfma_f32_16x16x32_f16((a), (b), (c), 0, 0, 0)

// Barrier draining LDS (lgkm) but NOT in-flight global prefetch loads.
#define LGKM_BARRIER() asm volatile("s_waitcnt lgkmcnt(0)\ns_barrier" ::: "memory")

// ---------------- ws layout (bytes) ----------------
#define WS_BT     0               // conv weights repacked [64][640] bf16 =    81,920
#define WS_WIHB   81920           // w_ih bf16 [512][64]                  =    65,536
#define WS_XG     8667136         // xgc f16 [64][128][128][4][8]         = 67,108,864
// (same max ws offset as all prior working rounds: 75,776,000 bytes)

// ============ prep: conv_w repack->bf16 + w_ih->bf16 ============
__global__ void prep_k(const float* __restrict__ conv_w, bf16* __restrict__ bt,
                       const float* __restrict__ w_ih, bf16* __restrict__ w_ihb) {
    int g = blockIdx.x * 256 + threadIdx.x;
    if (g < 64 * 640) {
        int f = g / 640, kk = g - f * 640;
        int k = kk >> 7, e = kk & 127;
        bt[g] = (bf16)conv_w[(f * 128 + e) * 5 + k];
    } else {
        int h = g - 64 * 640;
        if (h < 512 * 64) w_ihb[h] = (bf16)w_ih[h];
    }
}

// ============ kernel 1: embed-gather(f32->bf16) + conv + ReLU + pool4 + FUSED xg-GEMM ============
// Each WG owns (b, 32 consecutive t-rows) -- exactly the A-tile the input
// projection needs. Pooled tile staged in LDS (4.6KB), then mini-GEMM
// (32 x 512 x 64, 2 Mtiles x 8 Ntiles/wave x 2 kc) against L2-resident w_ihb,
// writing xgc directly in the LSTM chunk layout. Deletes the xg_gemm kernel,
// the emb_cvt kernel, and all pooled global traffic.
__global__ __launch_bounds__(256, 2) void conv_pool_k(
    const int* __restrict__ x, const float* __restrict__ emb,
    const bf16* __restrict__ bt, const float* __restrict__ conv_b,
    const bf16* __restrict__ w_ihb,
    const float* __restrict__ b_ih, const float* __restrict__ b_hh,
    f16* __restrict__ xg)
{
    __shared__ bf16 T[144 * 136];  // 136 = 128 + 8 pad
    __shared__ bf16 AP[32 * 72];   // pooled tile [tloc][f], 72 = 64 + 8 pad
    const int b   = blockIdx.x >> 5;
    const int l0  = (blockIdx.x & 31) << 7;
    const int tid = threadIdx.x;
    const int ln  = tid & 63, w = tid >> 6;
    const int l15 = ln & 15, quad = ln >> 4;
    const int f   = w * 16 + l15;

    bf16x8 bfrag[20];
    #pragma unroll
    for (int kc = 0; kc < 20; ++kc) {
        uint4 v = *(const uint4*)(bt + f * 640 + kc * 32 + quad * 8);
        bfrag[kc] = __builtin_bit_cast(bf16x8, v);
    }
    const float cb = conv_b[f];

    #pragma unroll
    for (int p = 0; p < 9; ++p) {
        int r = p * 16 + (tid >> 4);
        int cg = tid & 15;
        int token = l0 + r; if (token > 4095) token = 4095;
        int idx = x[b * 4096 + token];
        // direct f32 gather + in-register bf16 convert (same rounding as old emb_cvt)
        f32x4 v0 = *(const f32x4*)(emb + idx * 128 + cg * 8);
        f32x4 v1 = *(const f32x4*)(emb + idx * 128 + cg * 8 + 4);
        bf16x8 bv = (bf16x8){(bf16)v0[0], (bf16)v0[1], (bf16)v0[2], (bf16)v0[3],
                             (bf16)v1[0], (bf16)v1[1], (bf16)v1[2], (bf16)v1[3]};
        *(bf16x8*)(&T[r * 136 + cg * 8]) = bv;
    }
    __syncthreads();

    f32x4 acc[8];
    #pragma unroll
    for (int tm = 0; tm < 8; ++tm) acc[tm] = (f32x4){0.f, 0.f, 0.f, 0.f};

    #pragma unroll
    for (int kc = 0; kc < 20; ++kc) {
        const int ktap = kc >> 2;
        const int ecol = (kc & 3) * 32 + quad * 8;
        #pragma unroll
        for (int tm = 0; tm < 8; ++tm) {
            int row = tm * 16 + l15 + ktap;
            bf16x8 a = *(const bf16x8*)(&T[row * 136 + ecol]);
            acc[tm] = MFMA16(a, bfrag[kc], acc[tm]);
        }
    }

    // stage pooled tile to LDS (bf16 rounding identical to the old global pooled)
    #pragma unroll
    for (int tm = 0; tm < 8; ++tm) {
        float mx = fmaxf(fmaxf(acc[tm][0], acc[tm][1]), fmaxf(acc[tm][2], acc[tm][3]));
        mx = fmaxf(mx + cb, 0.f);
        int tloc = tm * 4 + quad;          // 0..31, bijective over (tm,quad)
        AP[tloc * 72 + f] = (bf16)mx;
    }
    __syncthreads();

    // ---- fused xg mini-GEMM: rows t = T0..T0+31, cols = 512 gates ----
    const int T0 = l0 >> 2;
    bf16x8 af[2][2];
    #pragma unroll
    for (int mt = 0; mt < 2; ++mt)
        #pragma unroll
        for (int kc = 0; kc < 2; ++kc)
            af[mt][kc] = *(const bf16x8*)(&AP[(mt * 16 + l15) * 72 + kc * 32 + quad * 8]);

    #pragma unroll
    for (int i = 0; i < 8; ++i) {
        const int nt = w * 8 + i;          // 32 N-tiles over 4 waves
        const int nn = nt * 16 + l15;
        uint4 v0 = *(const uint4*)(w_ihb + nn * 64 + quad * 8);
        uint4 v1 = *(const uint4*)(w_ihb + nn * 64 + 32 + quad * 8);
        bf16x8 bf0 = __builtin_bit_cast(bf16x8, v0);
        bf16x8 bf1 = __builtin_bit_cast(bf16x8, v1);
        const float bias = b_ih[nn] + b_hh[nn];
        const int unit = nn & 127, gate = nn >> 7;
        #pragma unroll
        for (int mt = 0; mt < 2; ++mt) {
            f32x4 a2 = (f32x4){0.f, 0.f, 0.f, 0.f};
            a2 = MFMA16(af[mt][0], bf0, a2);
            a2 = MFMA16(af[mt][1], bf1, a2);
            int t0 = T0 + mt * 16 + quad * 4;   // t0 % 4 == 0; rows t0..t0+3
            f16x4 sv = {(f16)(a2[0] + bias), (f16)(a2[1] + bias),
                        (f16)(a2[2] + bias), (f16)(a2[3] + bias)};
            size_t off = (((size_t)(b * 128 + (t0 >> 3)) * 128 + unit) * 4 + gate) * 8 + (t0 & 7);
            *(f16x4*)(xg + off) = sv;   // 8B store, (t0&7) in {0,4}; t=1023 slot unused by lstm
        }
    }
}

// ============ kernel 3: LSTM recurrence (f16 MFMA) + fc head ============
// BYTE-IDENTICAL to the R2 kernel (measured 463.7us). 16 WGs x 512 threads;
// WG handles 4 batches; wave w owns units w*16..w*16+15; 16 MFMA/wave/step.
__device__ inline float sigm_(float v) {
    return __builtin_amdgcn_rcpf(1.f + __builtin_amdgcn_exp2f(-1.4426950408889634f * v));
}
__device__ inline float tanh_(float v) {
    return 1.f - 2.f * __builtin_amdgcn_rcpf(1.f + __builtin_amdgcn_exp2f(2.8853901817779268f * v));
}

__global__ __launch_bounds__(512, 2) __attribute__((amdgpu_waves_per_eu(2, 2)))
void lstm_fc_k(
    const f16* __restrict__ xgc, const float* __restrict__ w_hh,
    const float* __restrict__ fc_w, const float* __restrict__ fc_b,
    float* __restrict__ out)
{
    __shared__ __align__(16) f16 hbuf[2 * 4 * 144];   // [p][bb][144]; 288B batch stride
    __shared__ float sm[8][2];
    const int b0   = blockIdx.x << 2;
    const int t    = threadIdx.x;     // 0..511
    const int w    = t >> 6;          // wave 0..7 -> units w*16..w*16+15
    const int ln   = t & 63;
    const int l15  = ln & 15, quad = ln >> 4;
    const int bb   = l15 >> 2;        // batch sub 0..3 (D col group / B col group)
    const int c    = l15 & 3;         // which of the 4 D-rows (regs) this lane owns
    const int u    = w * 16 + quad * 4 + c;  // unit handled by this lane

    // ---- A fragments: wa[g][kc], lane holds W_hh[g*128 + w*16 + l15][kc*32 + quad*8 + j]
    f16x8 wa[4][4];
    #pragma unroll
    for (int g = 0; g < 4; ++g)
        #pragma unroll
        for (int kc = 0; kc < 4; ++kc) {
            const float* wr = w_hh + (size_t)(g * 128 + w * 16 + l15) * 128 + kc * 32 + quad * 8;
            f32x4 v0 = *(const f32x4*)(wr);
            f32x4 v1 = *(const f32x4*)(wr + 4);
            wa[g][kc] = (f16x8){(f16)v0[0], (f16)v0[1], (f16)v0[2], (f16)v0[3],
                                (f16)v1[0], (f16)v1[1], (f16)v1[2], (f16)v1[3]};
        }
    #pragma unroll
    for (int g = 0; g < 4; ++g)
        #pragma unroll
        for (int kc = 0; kc < 4; ++kc) {
            uint4 r = __builtin_bit_cast(uint4, wa[g][kc]);
            asm volatile("" : "+v"(r.x), "+v"(r.y), "+v"(r.z), "+v"(r.w));  // pin
            wa[g][kc] = __builtin_bit_cast(f16x8, r);
        }

    // xq for this lane's (batch, unit): xgc[b0+bb][ch][u][g][j]
    const f16* xb = xgc + (size_t)(b0 + bb) * 524288 + (size_t)u * 32;
    f16x8 xq0 = *(const f16x8*)(xb);
    f16x8 xq1 = *(const f16x8*)(xb + 8);
    f16x8 xq2 = *(const f16x8*)(xb + 16);
    f16x8 xq3 = *(const f16x8*)(xb + 24);
    f16x8 nx0, nx1, nx2, nx3;

    // B-frag read bases (p=0/1) and h write addrs (write hp[p^1])
    const char* rb0 = (const char*)hbuf + bb * 288 + quad * 16;
    const char* rb1 = rb0 + 1152;
    f16* wb0 = (f16*)((char*)hbuf + 1152 + bb * 288 + u * 2);  // p=0 writes hp[1]
    f16* wb1 = (f16*)((char*)hbuf +        bb * 288 + u * 2);  // p=1 writes hp[0]

    if (t < 288) ((uint32_t*)hbuf)[t] = 0u;   // zero hp[0] (1152B)
    float cst = 0.f;
    LGKM_BARRIER();

    auto step = [&](int j, int p) {
        const char* rb = p ? rb1 : rb0;
        f16x8 hb0 = *(const f16x8*)(rb);
        f16x8 hb1 = *(const f16x8*)(rb + 64);
        f16x8 hb2 = *(const f16x8*)(rb + 128);
        f16x8 hb3 = *(const f16x8*)(rb + 192);
        f32x4 a0 = (f32x4){0.f, 0.f, 0.f, 0.f};
        f32x4 a1 = a0, a2 = a0, a3 = a0;
        a0 = MFMA16H(wa[0][0], hb0, a0); a1 = MFMA16H(wa[1][0], hb0, a1);
        a2 = MFMA16H(wa[2][0], hb0, a2); a3 = MFMA16H(wa[3][0], hb0, a3);
        a0 = MFMA16H(wa[0][1], hb1, a0); a1 = MFMA16H(wa[1][1], hb1, a1);
        a2 = MFMA16H(wa[2][1], hb1, a2); a3 = MFMA16H(wa[3][1], hb1, a3);
        a0 = MFMA16H(wa[0][2], hb2, a0); a1 = MFMA16H(wa[1][2], hb2, a1);
        a2 = MFMA16H(wa[2][2], hb2, a2); a3 = MFMA16H(wa[3][2], hb2, a3);
        a0 = MFMA16H(wa[0][3], hb3, a0); a1 = MFMA16H(wa[1][3], hb3, a1);
        a2 = MFMA16H(wa[2][3], hb3, a2); a3 = MFMA16H(wa[3][3], hb3, a3);
        // reg-select (compile-time element indices; c divergent -> cndmask)
        float s0a = (c & 1) ? a0[1] : a0[0], s0b = (c & 1) ? a0[3] : a0[2];
        float s1a = (c & 1) ? a1[1] : a1[0], s1b = (c & 1) ? a1[3] : a1[2];
        float s2a = (c & 1) ? a2[1] : a2[0], s2b = (c & 1) ? a2[3] : a2[2];
        float s3a = (c & 1) ? a3[1] : a3[0], s3b = (c & 1) ? a3[3] : a3[2];
        float p0 = (c & 2) ? s0b : s0a;
        float p1 = (c & 2) ? s1b : s1a;
        float p2 = (c & 2) ? s2b : s2a;
        float p3 = (c & 2) ? s3b : s3a;
        float ig = sigm_(p0 + (float)xq0[j]);
        float fg = sigm_(p1 + (float)xq1[j]);
        float gg = tanh_(p2 + (float)xq2[j]);
        float og = sigm_(p3 + (float)xq3[j]);
        cst = fg * cst + ig * gg;
        float hn = og * tanh_(cst);
        *(p ? wb1 : wb0) = (f16)hn;
        LGKM_BARRIER();
    };

    for (int ch = 0; ch < 127; ++ch) {
        // prefetch next chunk (vmcnt: not drained by the lgkm barrier)
        const f16* nb = xb + (size_t)(ch + 1) * 4096;
        nx0 = *(const f16x8*)(nb);
        nx1 = *(const f16x8*)(nb + 8);
        nx2 = *(const f16x8*)(nb + 16);
        nx3 = *(const f16x8*)(nb + 24);
        #pragma unroll
        for (int j = 0; j < 8; ++j) step(j, j & 1);
        xq0 = nx0; xq1 = nx1; xq2 = nx2; xq3 = nx3;
    }
    #pragma unroll
    for (int j = 0; j < 7; ++j) step(j, j & 1);   // steps 1016..1022; final h -> hp[1]

    // fc: out[b0+bbf][c2] = h_T . fc_w[c2] + fc_b[c2]   (h_T in hbuf[1])
    {
        int bbf = w >> 1, uhalf = w & 1;
        int uu = uhalf * 64 + ln;
        float hv = (float)*(const f16*)((const char*)hbuf + 1152 + bbf * 288 + uu * 2);
        float pr0 = hv * fc_w[uu];
        float pr1 = hv * fc_w[128 + uu];
        #pragma unroll
        for (int off = 32; off > 0; off >>= 1) {
            pr0 += __shfl_down(pr0, off, 64);
            pr1 += __shfl_down(pr1, off, 64);
        }
        if (ln == 0) { sm[w][0] = pr0; sm[w][1] = pr1; }
    }
    __syncthreads();
    if (t < 8) {
        int bbf = t >> 1, c2 = t & 1;
        out[(b0 + bbf) * 2 + c2] = sm[bbf * 2][c2] + sm[bbf * 2 + 1][c2] + fc_b[c2];
    }
}

// ============================ launcher ============================
extern "C" void kernel_launch(void* const* d_in, const int* in_sizes, int n_in,
                              void* d_out, int out_size, void* d_ws, size_t ws_size,
                              hipStream_t stream) {
    const int*   x      = (const int*)d_in[0];
    const float* emb    = (const float*)d_in[1];
    const float* conv_w = (const float*)d_in[2];
    const float* conv_b = (const float*)d_in[3];
    const float* w_ih   = (const float*)d_in[4];
    const float* w_hh   = (const float*)d_in[5];
    const float* b_ih   = (const float*)d_in[6];
    const float* b_hh   = (const float*)d_in[7];
    const float* fc_w   = (const float*)d_in[8];
    const float* fc_b   = (const float*)d_in[9];
    float* out = (float*)d_out;

    char* ws = (char*)d_ws;
    bf16* bt     = (bf16*)(ws + WS_BT);
    bf16* w_ihb  = (bf16*)(ws + WS_WIHB);
    f16*  xg     = (f16*)(ws + WS_XG);

    prep_k<<<288, 256, 0, stream>>>(conv_w, bt, w_ih, w_ihb);
    conv_pool_k<<<2048, 256, 0, stream>>>(x, emb, bt, conv_b, w_ihb, b_ih, b_hh, xg);
    lstm_fc_k<<<16, 512, 0, stream>>>(xg, w_hh, fc_w, fc_b, out);
}